// Round 5
// baseline (341.389 us; speedup 1.0000x reference)
//
#include <hip/hip_runtime.h>
#include <hip/hip_bf16.h>

#define N 8192
#define FIN 512
#define FOUT 256

typedef __attribute__((ext_vector_type(8))) short bf16x8;
typedef __attribute__((ext_vector_type(4))) float f32x4;

__device__ __forceinline__ unsigned short f2bf(float x) {
  unsigned int u = __float_as_uint(x);
  return (unsigned short)((u + 0x7FFFu + ((u >> 16) & 1u)) >> 16);
}

__device__ __forceinline__ void tile_barrier() {
  // Raw barrier: only drain LDS ops (As writes); att stores and B-prefetch
  // global loads stay in flight across the barrier (T4: never vmcnt(0)).
  asm volatile("s_waitcnt lgkmcnt(0)" ::: "memory");
  __builtin_amdgcn_s_barrier();
  __builtin_amdgcn_sched_barrier(0);
}

// ---------------------------------------------------------------------------
// K1: h = features(8192x512) @ W(512x256), fp32 vector GEMM, 64x64 tile.
// Epilogue also writes hT (bf16, [FOUT][N]) for the fused kernel's B loads.
// ---------------------------------------------------------------------------
__global__ __launch_bounds__(256) void gat_k1_gemm_h(
    const float* __restrict__ A, const float* __restrict__ W,
    float* __restrict__ h, unsigned short* __restrict__ hT) {
  __shared__ __align__(16) float As[16][68];
  __shared__ __align__(16) float Bs[16][64];
  const int tid = threadIdx.x;
  const int tx = tid & 15, ty = tid >> 4;
  const int nb = blockIdx.x * 64, mb = blockIdx.y * 64;
  float acc[4][4] = {};
  for (int k0 = 0; k0 < FIN; k0 += 16) {
#pragma unroll
    for (int i = 0; i < 4; ++i) {
      int e = tid + 256 * i;
      int m = e >> 4, k = e & 15;
      As[k][m] = A[(size_t)(mb + m) * FIN + k0 + k];
      int n2 = e & 63, k2 = e >> 6;
      Bs[k2][n2] = W[(size_t)(k0 + k2) * FOUT + nb + n2];
    }
    __syncthreads();
#pragma unroll
    for (int k = 0; k < 16; ++k) {
      float4 av = *reinterpret_cast<const float4*>(&As[k][ty * 4]);
      float4 bv = *reinterpret_cast<const float4*>(&Bs[k][tx * 4]);
      float aa[4] = {av.x, av.y, av.z, av.w};
      float bb[4] = {bv.x, bv.y, bv.z, bv.w};
#pragma unroll
      for (int i = 0; i < 4; ++i)
#pragma unroll
        for (int j = 0; j < 4; ++j) acc[i][j] = fmaf(aa[i], bb[j], acc[i][j]);
    }
    __syncthreads();
  }
#pragma unroll
  for (int i = 0; i < 4; ++i) {
    int m = mb + ty * 4 + i;
#pragma unroll
    for (int j = 0; j < 4; ++j) {
      int n = nb + tx * 4 + j;
      h[(size_t)m * FOUT + n] = acc[i][j];
      hT[(size_t)n * N + m] = f2bf(acc[i][j]);
    }
  }
}

// ---------------------------------------------------------------------------
// K2: hs[i] = h[i,:]@a[:256], hd[i] = h[i,:]@a[256:]. One wave per row.
// ---------------------------------------------------------------------------
__global__ __launch_bounds__(256) void gat_k2_hshd(
    const float* __restrict__ h, const float* __restrict__ a,
    float* __restrict__ hs, float* __restrict__ hd) {
  const int wid = threadIdx.x >> 6;
  const int lane = threadIdx.x & 63;
  const int row = blockIdx.x * 4 + wid;
  float ps = 0.f, pd = 0.f;
#pragma unroll
  for (int i = 0; i < 4; ++i) {
    int c = lane + 64 * i;
    float v = h[(size_t)row * FOUT + c];
    ps += v * a[c];
    pd += v * a[FOUT + c];
  }
#pragma unroll
  for (int off = 32; off >= 1; off >>= 1) {
    ps += __shfl_down(ps, off);
    pd += __shfl_down(pd, off);
  }
  if (lane == 0) {
    hs[row] = ps;
    hd[row] = pd;
  }
}

// ---------------------------------------------------------------------------
// FK v2: fused masked-softmax + (attention @ h).
// 512 blocks x 512 threads (8 waves), BM=16 rows/block, 2 blocks/CU.
// Thread owns row r=tid>>5; u=tid&31 splits as par=u>>4 (tile parity),
// slot=u&15 (float4 col slot). Per 128-col chunk q the thread loads ONE
// contiguous float4 of adj (tile 2q for par=0, 2q+1 for par=1) -> wave reads
// 2 rows x 512B contiguous (BW-bound streaming, K3-proven pattern).
// Phase 1: denominator s (no max-sub: logits O(6), f32-safe; masked = exact
// 0) + adjacency nibbles in bits[8]. 32-lane shfl_xor row reduce.
// Phase 2: 128 K-tiles, 64 unrolled pairs. Per tile: participants (par==t&1)
// recompute p = exp*inv from nib, store att float4 (fire-and-forget) +
// ds_write 4xbf16 into XOR-swizzled As[t&1]; raw barrier (lgkm only);
// MFMA 16x16x32 with A from LDS, B-fragments register-double-buffered
// straight from global hT (L2-resident; lane's 8 consecutive k = 16B load,
// prefetched one tile ahead, never drained at barriers).
// ---------------------------------------------------------------------------
__global__ __launch_bounds__(512, 4) void gat_fused(
    const float* __restrict__ adj, const float* __restrict__ hs,
    const float* __restrict__ hd, const unsigned short* __restrict__ hT,
    float* __restrict__ att, float* __restrict__ C) {
  __shared__ __align__(16) float hd_s[N];                 // 32 KB
  __shared__ __align__(16) unsigned short As[2][16 * 64]; // 2 x 2 KB

  const int tid = threadIdx.x;
  const int lane = tid & 63;
  const int wn = tid >> 6;  // wave 0..7 = col-tile of 32
  const int g = lane >> 4, rsel = lane & 15;
  const int row0 = blockIdx.x * 16;
  const int r = tid >> 5;       // owned row 0..15
  const int par = (tid >> 4) & 1;
  const int slot = tid & 15;

  // stage hd (16 floats/thread, contiguous wave segments)
#pragma unroll
  for (int i = 0; i < 4; ++i) {
    int j = (tid + 512 * i) * 4;
    *reinterpret_cast<float4*>(&hd_s[j]) =
        *reinterpret_cast<const float4*>(&hd[j]);
  }
  const float hsv = hs[row0 + r];
  __syncthreads();

  // ---- phase 1: denominator + adjacency nibbles ----
  unsigned int bits[8];
  float s = 0.f;
  const int hb = par * 64 + slot * 4;
  const float* arow = adj + (size_t)(row0 + r) * N + hb;
#pragma unroll
  for (int to = 0; to < 8; ++to) {
    unsigned int wb = 0;
#pragma unroll
    for (int qi = 0; qi < 8; ++qi) {
      int q = to * 8 + qi;
      float4 a4 = *reinterpret_cast<const float4*>(arow + q * 128);
      float4 h4 = *reinterpret_cast<const float4*>(&hd_s[q * 128 + hb]);
      float x0 = hsv + h4.x, x1 = hsv + h4.y;
      float x2 = hsv + h4.z, x3 = hsv + h4.w;
      float l0 = fmaxf(x0, 0.01f * x0), l1 = fmaxf(x1, 0.01f * x1);
      float l2 = fmaxf(x2, 0.01f * x2), l3 = fmaxf(x3, 0.01f * x3);
      unsigned int b0 = (a4.x != 0.f) ? 1u : 0u;
      unsigned int b1 = (a4.y != 0.f) ? 1u : 0u;
      unsigned int b2 = (a4.z != 0.f) ? 1u : 0u;
      unsigned int b3 = (a4.w != 0.f) ? 1u : 0u;
      s += (b0 ? __expf(l0) : 0.f) + (b1 ? __expf(l1) : 0.f) +
           (b2 ? __expf(l2) : 0.f) + (b3 ? __expf(l3) : 0.f);
      wb |= (b0 | (b1 << 1) | (b2 << 2) | (b3 << 3)) << (qi * 4);
    }
    bits[to] = wb;
  }
#pragma unroll
  for (int off = 16; off >= 1; off >>= 1) s += __shfl_xor(s, off);
  const float inv = 1.f / s;

  // ---- phase 2: att write + GEMM ----
  // B fragment pointers: lane needs hT[n][k..k+8), n = wn*32+f*16+rsel,
  // k = t*64 + ks*32 + g*8.
  const unsigned short* bp[2][2];
#pragma unroll
  for (int ks = 0; ks < 2; ++ks)
#pragma unroll
    for (int f = 0; f < 2; ++f)
      bp[ks][f] = hT + (size_t)(wn * 32 + f * 16 + rsel) * N + ks * 32 + g * 8;

  float* aoutb = att + (size_t)(row0 + r) * N + slot * 4;
  const int awbyte = r * 128 + (((slot >> 1) ^ (r & 7)) << 4) + (slot & 1) * 8;
  const int abase = rsel * 128;
  const int asw = (rsel & 7) << 4;

  f32x4 acc[2] = {};
  bf16x8 Bc00, Bc01, Bc10, Bc11, Bn00, Bn01, Bn10, Bn11;
  // prologue: B fragments for tile 0
  Bc00 = *reinterpret_cast<const bf16x8*>(bp[0][0]);
  Bc01 = *reinterpret_cast<const bf16x8*>(bp[0][1]);
  Bc10 = *reinterpret_cast<const bf16x8*>(bp[1][0]);
  Bc11 = *reinterpret_cast<const bf16x8*>(bp[1][1]);

#pragma unroll
  for (int to = 0; to < 8; ++to) {
    const unsigned int wb = bits[to];
    for (int tp = 0; tp < 8; ++tp) {
      const int t = to * 16 + tp * 2;
      // ======== even tile t (participants par==0, buffer As[0], B=Bc) ====
      {
        const int kb = (t + 1) * 64;  // prefetch tile t+1 -> Bn
        Bn00 = *reinterpret_cast<const bf16x8*>(bp[0][0] + kb);
        Bn01 = *reinterpret_cast<const bf16x8*>(bp[0][1] + kb);
        Bn10 = *reinterpret_cast<const bf16x8*>(bp[1][0] + kb);
        Bn11 = *reinterpret_cast<const bf16x8*>(bp[1][1] + kb);
      }
      if (par == 0) {
        unsigned int nib = wb >> (tp * 4);
        float4 h4 = *reinterpret_cast<const float4*>(&hd_s[t * 64 + slot * 4]);
        float x0 = hsv + h4.x, x1 = hsv + h4.y;
        float x2 = hsv + h4.z, x3 = hsv + h4.w;
        float p0 = (nib & 1) ? __expf(fmaxf(x0, 0.01f * x0)) * inv : 0.f;
        float p1 = (nib & 2) ? __expf(fmaxf(x1, 0.01f * x1)) * inv : 0.f;
        float p2 = (nib & 4) ? __expf(fmaxf(x2, 0.01f * x2)) * inv : 0.f;
        float p3 = (nib & 8) ? __expf(fmaxf(x3, 0.01f * x3)) * inv : 0.f;
        *reinterpret_cast<float4*>(aoutb + t * 64) =
            make_float4(p0, p1, p2, p3);
        uint2 pk;
        pk.x = (unsigned)f2bf(p0) | ((unsigned)f2bf(p1) << 16);
        pk.y = (unsigned)f2bf(p2) | ((unsigned)f2bf(p3) << 16);
        *reinterpret_cast<uint2*>(reinterpret_cast<char*>(As[0]) + awbyte) = pk;
      }
      tile_barrier();
      {
        const char* Ac = reinterpret_cast<const char*>(As[0]);
        bf16x8 af0 = *reinterpret_cast<const bf16x8*>(Ac + abase + ((g * 16) ^ asw));
        acc[0] = __builtin_amdgcn_mfma_f32_16x16x32_bf16(af0, Bc00, acc[0], 0, 0, 0);
        acc[1] = __builtin_amdgcn_mfma_f32_16x16x32_bf16(af0, Bc01, acc[1], 0, 0, 0);
        bf16x8 af1 = *reinterpret_cast<const bf16x8*>(Ac + abase + ((64 + g * 16) ^ asw));
        acc[0] = __builtin_amdgcn_mfma_f32_16x16x32_bf16(af1, Bc10, acc[0], 0, 0, 0);
        acc[1] = __builtin_amdgcn_mfma_f32_16x16x32_bf16(af1, Bc11, acc[1], 0, 0, 0);
      }
      // ======== odd tile t+1 (participants par==1, buffer As[1], B=Bn) ===
      {
        const int kb = ((t + 2) & 127) * 64;  // prefetch tile t+2 -> Bc
        Bc00 = *reinterpret_cast<const bf16x8*>(bp[0][0] + kb);
        Bc01 = *reinterpret_cast<const bf16x8*>(bp[0][1] + kb);
        Bc10 = *reinterpret_cast<const bf16x8*>(bp[1][0] + kb);
        Bc11 = *reinterpret_cast<const bf16x8*>(bp[1][1] + kb);
      }
      if (par == 1) {
        unsigned int nib = wb >> (tp * 4);
        float4 h4 =
            *reinterpret_cast<const float4*>(&hd_s[(t + 1) * 64 + slot * 4]);
        float x0 = hsv + h4.x, x1 = hsv + h4.y;
        float x2 = hsv + h4.z, x3 = hsv + h4.w;
        float p0 = (nib & 1) ? __expf(fmaxf(x0, 0.01f * x0)) * inv : 0.f;
        float p1 = (nib & 2) ? __expf(fmaxf(x1, 0.01f * x1)) * inv : 0.f;
        float p2 = (nib & 4) ? __expf(fmaxf(x2, 0.01f * x2)) * inv : 0.f;
        float p3 = (nib & 8) ? __expf(fmaxf(x3, 0.01f * x3)) * inv : 0.f;
        *reinterpret_cast<float4*>(aoutb + (t + 1) * 64) =
            make_float4(p0, p1, p2, p3);
        uint2 pk;
        pk.x = (unsigned)f2bf(p0) | ((unsigned)f2bf(p1) << 16);
        pk.y = (unsigned)f2bf(p2) | ((unsigned)f2bf(p3) << 16);
        *reinterpret_cast<uint2*>(reinterpret_cast<char*>(As[1]) + awbyte) = pk;
      }
      tile_barrier();
      {
        const char* Ac = reinterpret_cast<const char*>(As[1]);
        bf16x8 af0 = *reinterpret_cast<const bf16x8*>(Ac + abase + ((g * 16) ^ asw));
        acc[0] = __builtin_amdgcn_mfma_f32_16x16x32_bf16(af0, Bn00, acc[0], 0, 0, 0);
        acc[1] = __builtin_amdgcn_mfma_f32_16x16x32_bf16(af0, Bn01, acc[1], 0, 0, 0);
        bf16x8 af1 = *reinterpret_cast<const bf16x8*>(Ac + abase + ((64 + g * 16) ^ asw));
        acc[0] = __builtin_amdgcn_mfma_f32_16x16x32_bf16(af1, Bn10, acc[0], 0, 0, 0);
        acc[1] = __builtin_amdgcn_mfma_f32_16x16x32_bf16(af1, Bn11, acc[1], 0, 0, 0);
      }
    }
  }
  // C write: C/D layout col=lane&15, row=(lane>>4)*4+reg
#pragma unroll
  for (int f = 0; f < 2; ++f)
#pragma unroll
    for (int rr = 0; rr < 4; ++rr) {
      int row = row0 + g * 4 + rr;
      int col = wn * 32 + f * 16 + rsel;
      C[(size_t)row * FOUT + col] = acc[f][rr];
    }
}

extern "C" void kernel_launch(void* const* d_in, const int* in_sizes, int n_in,
                              void* d_out, int out_size, void* d_ws, size_t ws_size,
                              hipStream_t stream) {
  const float* features = (const float*)d_in[0];
  const float* adj = (const float*)d_in[1];
  const float* W = (const float*)d_in[2];
  const float* a = (const float*)d_in[3];

  float* out = (float*)d_out;           // [N][FOUT]
  float* att = out + (size_t)N * FOUT;  // [N][N]

  char* ws = (char*)d_ws;
  float* h = (float*)ws;                                              // 8 MB
  unsigned short* hT = (unsigned short*)(ws + (size_t)N * FOUT * 4);  // 4 MB
  float* hs = (float*)(ws + (size_t)N * FOUT * 4 + (size_t)N * FOUT * 2);
  float* hd = hs + N;

  hipLaunchKernelGGL(gat_k1_gemm_h, dim3(FOUT / 64, N / 64), dim3(256), 0,
                     stream, features, W, h, hT);
  hipLaunchKernelGGL(gat_k2_hshd, dim3(N / 4), dim3(256), 0, stream, h, a, hs,
                     hd);
  hipLaunchKernelGGL(gat_fused, dim3(N / 16), dim3(512), 0, stream, adj, hs,
                     hd, hT, att, out);
}

// Round 6
// 250.713 us; speedup vs baseline: 1.3617x; 1.3617x over previous
//
#include <hip/hip_runtime.h>
#include <hip/hip_bf16.h>

#define N 8192
#define FIN 512
#define FOUT 256

typedef __attribute__((ext_vector_type(8))) short bf16x8;
typedef __attribute__((ext_vector_type(4))) float f32x4;

__device__ __forceinline__ unsigned short f2bf(float x) {
  unsigned int u = __float_as_uint(x);
  return (unsigned short)((u + 0x7FFFu + ((u >> 16) & 1u)) >> 16);
}

// ---------------------------------------------------------------------------
// K1: h = features(8192x512) @ W(512x256), fp32 vector GEMM, 64x64 tile.
// Epilogue also writes hT (bf16, [FOUT][N]) for K4's B-operand staging.
// ---------------------------------------------------------------------------
__global__ __launch_bounds__(256) void gat_k1_gemm_h(
    const float* __restrict__ A, const float* __restrict__ W,
    float* __restrict__ h, unsigned short* __restrict__ hT) {
  __shared__ __align__(16) float As[16][68];
  __shared__ __align__(16) float Bs[16][64];
  const int tid = threadIdx.x;
  const int tx = tid & 15, ty = tid >> 4;
  const int nb = blockIdx.x * 64, mb = blockIdx.y * 64;
  float acc[4][4] = {};
  for (int k0 = 0; k0 < FIN; k0 += 16) {
#pragma unroll
    for (int i = 0; i < 4; ++i) {
      int e = tid + 256 * i;
      int m = e >> 4, k = e & 15;
      As[k][m] = A[(size_t)(mb + m) * FIN + k0 + k];
      int n2 = e & 63, k2 = e >> 6;
      Bs[k2][n2] = W[(size_t)(k0 + k2) * FOUT + nb + n2];
    }
    __syncthreads();
#pragma unroll
    for (int k = 0; k < 16; ++k) {
      float4 av = *reinterpret_cast<const float4*>(&As[k][ty * 4]);
      float4 bv = *reinterpret_cast<const float4*>(&Bs[k][tx * 4]);
      float aa[4] = {av.x, av.y, av.z, av.w};
      float bb[4] = {bv.x, bv.y, bv.z, bv.w};
#pragma unroll
      for (int i = 0; i < 4; ++i)
#pragma unroll
        for (int j = 0; j < 4; ++j) acc[i][j] = fmaf(aa[i], bb[j], acc[i][j]);
    }
    __syncthreads();
  }
#pragma unroll
  for (int i = 0; i < 4; ++i) {
    int m = mb + ty * 4 + i;
#pragma unroll
    for (int j = 0; j < 4; ++j) {
      int n = nb + tx * 4 + j;
      h[(size_t)m * FOUT + n] = acc[i][j];
      hT[(size_t)n * N + m] = f2bf(acc[i][j]);
    }
  }
}

// ---------------------------------------------------------------------------
// K2: hs[i] = h[i,:]@a[:256], hd[i] = h[i,:]@a[256:]. One wave per row.
// Also zero-fills `out` (8 MB) so K4's split-K atomics can accumulate.
// ---------------------------------------------------------------------------
__global__ __launch_bounds__(256) void gat_k2_hshd(
    const float* __restrict__ h, const float* __restrict__ a,
    float* __restrict__ hs, float* __restrict__ hd, float* __restrict__ out) {
  const int gid = blockIdx.x * 256 + threadIdx.x;
  *reinterpret_cast<float4*>(out + (size_t)gid * 4) =
      make_float4(0.f, 0.f, 0.f, 0.f);

  const int wid = threadIdx.x >> 6;
  const int lane = threadIdx.x & 63;
  const int row = blockIdx.x * 4 + wid;
  float ps = 0.f, pd = 0.f;
#pragma unroll
  for (int i = 0; i < 4; ++i) {
    int c = lane + 64 * i;
    float v = h[(size_t)row * FOUT + c];
    ps += v * a[c];
    pd += v * a[FOUT + c];
  }
#pragma unroll
  for (int off = 32; off >= 1; off >>= 1) {
    ps += __shfl_down(ps, off);
    pd += __shfl_down(pd, off);
  }
  if (lane == 0) {
    hs[row] = ps;
    hd[row] = pd;
  }
}

// ---------------------------------------------------------------------------
// K3: masked softmax rows, float4-vectorized. One streaming pass of adj per
// row; 32 logits/thread in registers. 8 rows/block amortize the hd LDS stage.
// ---------------------------------------------------------------------------
__global__ __launch_bounds__(256) void gat_k3_attn(
    const float* __restrict__ adj, const float* __restrict__ hs,
    const float* __restrict__ hd, float* __restrict__ att) {
  __shared__ __align__(16) float hd_s[N];  // 32 KB
  __shared__ float red[4];
  const int tid = threadIdx.x;
  const int lane = tid & 63, wid = tid >> 6;
#pragma unroll
  for (int i = 0; i < 8; ++i) {
    int j = tid * 4 + 1024 * i;
    *reinterpret_cast<float4*>(&hd_s[j]) =
        *reinterpret_cast<const float4*>(&hd[j]);
  }
  __syncthreads();
  const int row0 = blockIdx.x * 8;
  for (int r = 0; r < 8; ++r) {
    const int row = row0 + r;
    const float hsv = hs[row];
    const float* arow = adj + (size_t)row * N;
    float4 l[8];
    float m = -__builtin_inff();
#pragma unroll
    for (int i = 0; i < 8; ++i) {
      int j = tid * 4 + 1024 * i;
      float4 a4 = *reinterpret_cast<const float4*>(&arow[j]);
      float4 h4 = *reinterpret_cast<const float4*>(&hd_s[j]);
      float4 lv;
      float x;
      x = hsv + h4.x; x = x > 0.f ? x : 0.01f * x;
      lv.x = (a4.x != 0.f) ? x : -__builtin_inff();
      x = hsv + h4.y; x = x > 0.f ? x : 0.01f * x;
      lv.y = (a4.y != 0.f) ? x : -__builtin_inff();
      x = hsv + h4.z; x = x > 0.f ? x : 0.01f * x;
      lv.z = (a4.z != 0.f) ? x : -__builtin_inff();
      x = hsv + h4.w; x = x > 0.f ? x : 0.01f * x;
      lv.w = (a4.w != 0.f) ? x : -__builtin_inff();
      l[i] = lv;
      m = fmaxf(m, fmaxf(fmaxf(lv.x, lv.y), fmaxf(lv.z, lv.w)));
    }
#pragma unroll
    for (int off = 32; off >= 1; off >>= 1) m = fmaxf(m, __shfl_down(m, off));
    if (lane == 0) red[wid] = m;
    __syncthreads();
    m = fmaxf(fmaxf(red[0], red[1]), fmaxf(red[2], red[3]));
    __syncthreads();
    float s = 0.f;
#pragma unroll
    for (int i = 0; i < 8; ++i) {
      float4 lv = l[i];
      lv.x = __expf(lv.x - m);
      lv.y = __expf(lv.y - m);
      lv.z = __expf(lv.z - m);
      lv.w = __expf(lv.w - m);
      l[i] = lv;
      s += lv.x + lv.y + lv.z + lv.w;
    }
#pragma unroll
    for (int off = 32; off >= 1; off >>= 1) s += __shfl_down(s, off);
    if (lane == 0) red[wid] = s;
    __syncthreads();
    s = red[0] + red[1] + red[2] + red[3];
    __syncthreads();
    const float inv = 1.f / s;
    float* orow = att + (size_t)row * N;
#pragma unroll
    for (int i = 0; i < 8; ++i) {
      float4 lv = l[i];
      lv.x *= inv; lv.y *= inv; lv.z *= inv; lv.w *= inv;
      *reinterpret_cast<float4*>(&orow[tid * 4 + 1024 * i]) = lv;
    }
  }
}

// ---------------------------------------------------------------------------
// K4 v3: output = attention @ h via bf16 MFMA 16x16x32, split-K + split-N.
// BM=64, BN=128, K-split=2 (4096/block), BK=64. Grid = 128 row-blocks x
// 2 n-halves x 2 k-halves = 512 blocks of 512 threads (8 waves, wave tile
// 32x32, acc 2x2). LDS 48 KB -> 2 blocks/CU: two INDEPENDENT barrier
// domains per CU cover each other's prefetch-latency stalls (the R3 K4 was
// 1 block/CU and barrier-bound). XCD mapping: xcd=id&7 fixes (n-half,
// k-half) per XCD so each XCD's 1 MB hT panel is L2-resident; att read
// once aggregate. Partials via f32 atomicAdd into out (zeroed by K2).
// Reg-staged double-buffered 1-barrier pipeline; XOR-swizzled LDS
// (16B-slot bits of row byte offset ^= (row&7)<<4).
// ---------------------------------------------------------------------------
__global__ __launch_bounds__(512, 2) void gat_k4_out(
    const float* __restrict__ att, const unsigned short* __restrict__ hT,
    float* __restrict__ C) {
  __shared__ __align__(16) unsigned short As[2][64 * 64];   // 2 x 8 KB
  __shared__ __align__(16) unsigned short Bs[2][128 * 64];  // 2 x 16 KB
  const int tid = threadIdx.x;
  const int lane = tid & 63;
  const int wid = tid >> 6;  // 0..7
  const int wm = wid >> 2, wn = wid & 3;
  const int g = lane >> 4, rsel = lane & 15;
  // block mapping: xcd = id&7 -> (nh, kh, row-half); pos = id>>3 (0..63)
  const int id = blockIdx.x;
  const int xcd = id & 7, pos = id >> 3;
  const int nh = xcd & 1, kh = (xcd >> 1) & 1;
  const int row0 = ((xcd >> 2) * 64 + pos) * 64;
  const int nb = nh * 128;
  const int kbase = kh * 4096;

  // A staging (2 float4/thread): e = tid+512*i -> row r=e>>4, slot p=e&15
  const float* asrc[2];
  int abyte[2];
#pragma unroll
  for (int i = 0; i < 2; ++i) {
    int e = tid + 512 * i;
    int r = e >> 4, p = e & 15;
    asrc[i] = att + (size_t)(row0 + r) * N + kbase + p * 4;
    abyte[i] = r * 128 + ((p * 8) ^ ((r & 7) << 4));
  }
  // B staging (2 uint4/thread): s = tid+512*i -> n=s>>3, kg=s&7, src presw.
  const unsigned short* bsrc[2];
  int bofs[2];
#pragma unroll
  for (int i = 0; i < 2; ++i) {
    int s = tid + 512 * i;
    int n = s >> 3, kg = s & 7;
    int kgs = kg ^ (n & 7);
    bsrc[i] = hT + (size_t)(nb + n) * N + kbase + kgs * 8;
    bofs[i] = s * 16;
  }

  f32x4 acc[2][2] = {};
  float4 aA0, aA1;
  uint4 bB0, bB1;

  // prologue: load + write tile 0
  aA0 = *reinterpret_cast<const float4*>(asrc[0]);
  aA1 = *reinterpret_cast<const float4*>(asrc[1]);
  bB0 = *reinterpret_cast<const uint4*>(bsrc[0]);
  bB1 = *reinterpret_cast<const uint4*>(bsrc[1]);
  {
    uint2 pk;
    pk.x = (unsigned)f2bf(aA0.x) | ((unsigned)f2bf(aA0.y) << 16);
    pk.y = (unsigned)f2bf(aA0.z) | ((unsigned)f2bf(aA0.w) << 16);
    *reinterpret_cast<uint2*>(reinterpret_cast<char*>(As[0]) + abyte[0]) = pk;
    pk.x = (unsigned)f2bf(aA1.x) | ((unsigned)f2bf(aA1.y) << 16);
    pk.y = (unsigned)f2bf(aA1.z) | ((unsigned)f2bf(aA1.w) << 16);
    *reinterpret_cast<uint2*>(reinterpret_cast<char*>(As[0]) + abyte[1]) = pk;
    *reinterpret_cast<uint4*>(reinterpret_cast<char*>(Bs[0]) + bofs[0]) = bB0;
    *reinterpret_cast<uint4*>(reinterpret_cast<char*>(Bs[0]) + bofs[1]) = bB1;
  }

  int cur = 0;
  for (int t = 0; t < 64; ++t) {
    const int knext = (t + 1) * 64;
    if (t < 63) {  // issue next tile's loads early (hide under MFMA)
      aA0 = *reinterpret_cast<const float4*>(asrc[0] + knext);
      aA1 = *reinterpret_cast<const float4*>(asrc[1] + knext);
      bB0 = *reinterpret_cast<const uint4*>(bsrc[0] + knext);
      bB1 = *reinterpret_cast<const uint4*>(bsrc[1] + knext);
    }
    __syncthreads();
    const char* Ac = reinterpret_cast<const char*>(As[cur]);
    const char* Bc = reinterpret_cast<const char*>(Bs[cur]);
#pragma unroll
    for (int ks = 0; ks < 2; ++ks) {
      bf16x8 af[2], bg[2];
#pragma unroll
      for (int f = 0; f < 2; ++f) {
        int r = wm * 32 + f * 16 + rsel;
        af[f] = *reinterpret_cast<const bf16x8*>(
            Ac + r * 128 + ((ks * 64 + g * 16) ^ ((r & 7) << 4)));
        int n = wn * 32 + f * 16 + rsel;
        bg[f] = *reinterpret_cast<const bf16x8*>(
            Bc + n * 128 + ((ks * 64 + g * 16) ^ ((n & 7) << 4)));
      }
#pragma unroll
      for (int i = 0; i < 2; ++i)
#pragma unroll
        for (int j = 0; j < 2; ++j)
          acc[i][j] = __builtin_amdgcn_mfma_f32_16x16x32_bf16(af[i], bg[j],
                                                              acc[i][j], 0, 0, 0);
    }
    if (t < 63) {
      char* An = reinterpret_cast<char*>(As[cur ^ 1]);
      char* Bn = reinterpret_cast<char*>(Bs[cur ^ 1]);
      uint2 pk;
      pk.x = (unsigned)f2bf(aA0.x) | ((unsigned)f2bf(aA0.y) << 16);
      pk.y = (unsigned)f2bf(aA0.z) | ((unsigned)f2bf(aA0.w) << 16);
      *reinterpret_cast<uint2*>(An + abyte[0]) = pk;
      pk.x = (unsigned)f2bf(aA1.x) | ((unsigned)f2bf(aA1.y) << 16);
      pk.y = (unsigned)f2bf(aA1.z) | ((unsigned)f2bf(aA1.w) << 16);
      *reinterpret_cast<uint2*>(An + abyte[1]) = pk;
      *reinterpret_cast<uint4*>(Bn + bofs[0]) = bB0;
      *reinterpret_cast<uint4*>(Bn + bofs[1]) = bB1;
      cur ^= 1;
    }
  }
  // epilogue: split-K accumulate. C/D layout col=lane&15, row=(lane>>4)*4+reg
#pragma unroll
  for (int i = 0; i < 2; ++i)
#pragma unroll
    for (int j = 0; j < 2; ++j)
#pragma unroll
      for (int r = 0; r < 4; ++r) {
        int row = row0 + wm * 32 + i * 16 + g * 4 + r;
        int col = nb + wn * 32 + j * 16 + rsel;
        atomicAdd(&C[(size_t)row * FOUT + col], acc[i][j][r]);
      }
}

extern "C" void kernel_launch(void* const* d_in, const int* in_sizes, int n_in,
                              void* d_out, int out_size, void* d_ws, size_t ws_size,
                              hipStream_t stream) {
  const float* features = (const float*)d_in[0];
  const float* adj = (const float*)d_in[1];
  const float* W = (const float*)d_in[2];
  const float* a = (const float*)d_in[3];

  float* out = (float*)d_out;           // [N][FOUT]
  float* att = out + (size_t)N * FOUT;  // [N][N]

  char* ws = (char*)d_ws;
  float* h = (float*)ws;                                              // 8 MB
  unsigned short* hT = (unsigned short*)(ws + (size_t)N * FOUT * 4);  // 4 MB
  float* hs = (float*)(ws + (size_t)N * FOUT * 4 + (size_t)N * FOUT * 2);
  float* hd = hs + N;

  hipLaunchKernelGGL(gat_k1_gemm_h, dim3(FOUT / 64, N / 64), dim3(256), 0,
                     stream, features, W, h, hT);
  hipLaunchKernelGGL(gat_k2_hshd, dim3(N / 4), dim3(256), 0, stream, h, a, hs,
                     hd, out);
  hipLaunchKernelGGL(gat_k3_attn, dim3(N / 8), dim3(256), 0, stream, adj, hs,
                     hd, att);
  hipLaunchKernelGGL(gat_k4_out, dim3(512), dim3(512), 0, stream, att, hT,
                     out);
}